// Round 4
// baseline (5954.753 us; speedup 1.0000x reference)
//
#include <hip/hip_runtime.h>

typedef _Float16 half_t;
typedef _Float16 half8 __attribute__((ext_vector_type(8)));
typedef _Float16 half4 __attribute__((ext_vector_type(4)));
typedef float float4v __attribute__((ext_vector_type(4)));

#define BB    256
#define SS    512
#define IND   64
#define HH    1024
#define HEADD 128
#define OUTD  64
#define NKT   34                      // K tiles of 32: 32 (h) + 2 (x)
#define WLDS_HALVES (4 * NKT * 512)   // 69632 halves = 139264 B
#define PRE_STRIDE 68                 // padded float stride
#define DP_OFF   (WLDS_HALVES * 2 + 4 * 16 * PRE_STRIDE * 4)  // 156672
#define FLAG_OFF (DP_OFF + 3 * 64 * 4 * 4)                    // 159744
#define SMEM_BYTES (FLAG_OFF + 32)                            // 159776 B
#define BUFV (BB * HH)                // halves per h step-buffer (512 KB)
// g_sync layout (words):
//  [(mtile*64+jtile)*32]               slot line: 4 u16 per-gate-wave flags
//  [8192 + mtile*512 + copy*32 + q]    go words: chunk-q running min (16 copies)
//  [10240 + mtile*32]                  dcnt (dense1 completion counter)
#define GO_OFF   8192
#define DCNT_OFF 10240
#define SYNC_WORDS 10368

#define MFMA16(a, b, acc) __builtin_amdgcn_mfma_f32_16x16x32_f16(a, b, acc, 0, 0, 0)

// Rotating write-once state in device globals: every address is written at
// most once per dispatch before being read -> plain cached loads are
// coherence-safe (producer sc-stores land at LLC; consumer caches are
// invalidated at dispatch start and never touch these lines beforehand).
__device__ half_t g_hA[(size_t)(SS + 1) * BUFV];          // ~263 MB
__device__ half_t g_dbuf[(size_t)SS * 256 * HEADD];       // ~33.5 MB
__device__ unsigned int g_sync[SYNC_WORDS];

__device__ __forceinline__ void astore8(half_t* p, half4 v) {
  union { half4 h; unsigned long long u; } r; r.h = v;
  __hip_atomic_store((unsigned long long*)p, r.u, __ATOMIC_RELAXED,
                     __HIP_MEMORY_SCOPE_AGENT);
}
__device__ __forceinline__ void astore2(half_t* p, half_t v) {
  union { half_t h; unsigned short u; } r; r.h = v;
  __hip_atomic_store((unsigned short*)p, r.u, __ATOMIC_RELAXED,
                     __HIP_MEMORY_SCOPE_AGENT);
}

// ---------- prologue ----------

__global__ __launch_bounds__(256) void init_state() {
  const size_t i = (size_t)blockIdx.x * 256 + threadIdx.x;  // 65536 threads
  *(unsigned long long*)(g_hA + i * 4) = 0ULL;              // zero buffer 0
  if (blockIdx.x == 0)
    for (int j = threadIdx.x; j < SYNC_WORDS; j += 256) g_sync[j] = 0;
}

// x[B][S][IN] fp32 -> xA[t][mt][kt][lane][8] fp16 (A-fragment order per step)
__global__ __launch_bounds__(256) void pack_x(const float* __restrict__ x,
                                              half_t* __restrict__ xA) {
  const int t = blockIdx.x, mt = blockIdx.y;
  const int tid = threadIdx.x;
  const int kt = tid >> 7;
  const int lane = (tid >> 1) & 63;
  const int jh = (tid & 1) * 4;
  const int row = mt * 16 + (lane & 15);
  const int k = kt * 32 + (lane >> 4) * 8 + jh;
  const float* s = x + (size_t)row * SS * IND + (size_t)t * IND + k;
  half_t* d = xA + (((size_t)t * 16 + mt) * 2 + kt) * 512 + lane * 8 + jh;
  d[0] = (half_t)s[0]; d[1] = (half_t)s[1];
  d[2] = (half_t)s[2]; d[3] = (half_t)s[3];
}

// row-major fp32 [N][K] -> fp16 B-fragment order [cb][kt][lane][8]
__global__ __launch_bounds__(256) void frag_pack(const float* __restrict__ src,
                                                 half_t* __restrict__ dst, int K) {
  const int cb = blockIdx.x;
  const int tid = threadIdx.x;
  const int lane = tid & 63;
  const int u = tid >> 6;
  const int nkt = K >> 5;
  const int row = cb * 16 + (lane & 15);
  for (int kt = u; kt < nkt; kt += 4) {
    const int k = kt * 32 + (lane >> 4) * 8;
    const float* s = src + (size_t)row * K + k;
    half8 h;
    #pragma unroll
    for (int j = 0; j < 8; ++j) h[j] = (half_t)s[j];
    *(half8*)(dst + ((size_t)cb * nkt + kt) * 512 + lane * 8) = h;
  }
}

// one K-tile of the gates GEMM (A from global, B from LDS)
#define GKT(kt)                                                               \
  {                                                                           \
    const half8 av = *(const half8*)(ap + (size_t)(kt) * 512);                \
    a0 = MFMA16(av, *(const half8*)(bp + (size_t)(0 * NKT + (kt)) * 512), a0);\
    a1 = MFMA16(av, *(const half8*)(bp + (size_t)(1 * NKT + (kt)) * 512), a1);\
    a2 = MFMA16(av, *(const half8*)(bp + (size_t)(2 * NKT + (kt)) * 512), a2);\
    a3 = MFMA16(av, *(const half8*)(bp + (size_t)(3 * NKT + (kt)) * 512), a3);\
  }

// ---------- persistent LSTM kernel (cooperative, 256 WGs = 1/CU) ----------
// 512 threads/WG. Waves 0..3: recurrence (gate g = wave), no barriers in the
// steady state; per-wave u16 release flags. Wave 5 of jtile 63 = aggregator:
// continuously publishes per-chunk running-min progress (chunk q = jtiles
// 16q..16q+15 = h k-tiles 8q..8q+7) via plain broadcast stores (no RMW).
// Consumers take the R2 straight-loop fast path when all chunks are ready,
// else overlap early-chunk MFMAs with the stragglers. Waves 4..7: dense head
// (dense1 self-polls its own chunk word -> off critical path).
__global__ __launch_bounds__(512, 2) void lstm_persistent(
    const float* __restrict__ W_hh, const float* __restrict__ W_ih,
    const float* __restrict__ b_ih, const float* __restrict__ b_hh,
    const half_t* __restrict__ xA, const half_t* __restrict__ Wd_f,
    const float* __restrict__ bd, const half_t* __restrict__ Wd2_f,
    const float* __restrict__ bd2, float* __restrict__ out) {
  extern __shared__ char smem[];
  half_t* Wlds = (half_t*)smem;
  float* pre = (float*)(smem + (size_t)WLDS_HALVES * 2);
  float* dp = (float*)(smem + DP_OFF);          // dense1 partials [3][64][4]
  unsigned* flg = (unsigned*)(smem + FLAG_OFF); // [0..2]=dflag [4]=ack

  const int wg = blockIdx.x;
  const int mtile = wg >> 6;          // 0..3  (batch rows m0..m0+63)
  const int jtile = wg & 63;          // 0..63 (h cols j0..j0+15, all 4 gates)
  const int j0 = jtile * 16;
  const int tid = threadIdx.x;
  const int wave = tid >> 6;
  const int lane = tid & 63;
  const int rn = lane & 15;
  const int kq = lane >> 4;

  // ---- stage W gate-slice into LDS in B-fragment order (8 waves) ----
  {
    const int g = wave & 3;
    const int row = g * HH + j0 + rn;
    for (int kt = (wave >> 2); kt < NKT; kt += 2) {
      const int k = kt * 32 + kq * 8;
      const float* s = (k < HH) ? (W_hh + (size_t)row * HH + k)
                                : (W_ih + (size_t)row * IND + (k - HH));
      half8 hv;
      #pragma unroll
      for (int j = 0; j < 8; ++j) hv[j] = (half_t)s[j];
      *(half8*)(Wlds + ((size_t)g * NKT + kt) * 512 + lane * 8) = hv;
    }
  }
  if (tid < 8) flg[tid] = 0;
  __syncthreads();   // only barrier in the kernel

  unsigned short* slotp =
      (unsigned short*)(g_sync + ((size_t)(mtile * 64 + jtile)) * 32);
  unsigned int* go_base = g_sync + GO_OFF + mtile * 512;
  const unsigned int* goline = go_base + (jtile & 15) * 32;  // 4 chunk words
  unsigned int* dcnt = g_sync + DCNT_OFF + mtile * 32;

  if (wave < 4) {
    // ================= recurrence (gate) waves =================
    const int crow = lane >> 2;         // 0..15 row within wave's block
    const int hl = (lane & 3) * 4;      // col base 0,4,8,12
    float bsum[4][4];
    #pragma unroll
    for (int g = 0; g < 4; ++g) {
      const float4v bi = *(const float4v*)(b_ih + g * HH + j0 + hl);
      const float4v bh = *(const float4v*)(b_hh + g * HH + j0 + hl);
      #pragma unroll
      for (int j = 0; j < 4; ++j) bsum[g][j] = bi[j] + bh[j];
    }
    float4v creg = {0.f, 0.f, 0.f, 0.f};

    const int mtA = mtile * 4 + wave;   // wave's 16-row block (global mt 0..15)
    float* pw = pre + wave * (16 * PRE_STRIDE);

    const int col_s = j0 + hl;
    const int ktw = col_s >> 5;
    const int kqw = (col_s & 31) >> 3;
    const int jw = col_s & 7;
    const size_t hoff =
        (((size_t)(mtA * 32 + ktw)) * 64 + kqw * 16 + crow) * 8 + jw;

    const half_t* habase = g_hA + ((size_t)mtA * 32) * 512 + lane * 8;
    const half_t* bp = Wlds + lane * 8;
    unsigned short* myslot = slotp + wave;

    for (int t = 0; t < SS; ++t) {
      // ---- early snapshot of the 4 chunk go-words (hide LLC latency) ----
      unsigned g0 = 0, g1 = 0, g2 = 0, g3 = 0;
      if (t >= 1) {
        const unsigned long long v01 = __hip_atomic_load(
            (const unsigned long long*)goline, __ATOMIC_RELAXED,
            __HIP_MEMORY_SCOPE_AGENT);
        const unsigned long long v23 = __hip_atomic_load(
            (const unsigned long long*)(goline + 2), __ATOMIC_RELAXED,
            __HIP_MEMORY_SCOPE_AGENT);
        g0 = (unsigned)v01; g1 = (unsigned)(v01 >> 32);
        g2 = (unsigned)v23; g3 = (unsigned)(v23 >> 32);
      }

      float4v a0 = {0.f, 0.f, 0.f, 0.f}, a1 = {0.f, 0.f, 0.f, 0.f};
      float4v a2 = {0.f, 0.f, 0.f, 0.f}, a3 = {0.f, 0.f, 0.f, 0.f};

      // ---- x part first: independent of h_t, hides work under the wait ----
      const half_t* xp = xA + (((size_t)t * 16 + mtA) * 2) * 512 + lane * 8;
      {
        const half8 xv0 = *(const half8*)xp;
        const half8 xv1 = *(const half8*)(xp + 512);
        a0 = MFMA16(xv0, *(const half8*)(bp + (size_t)(0 * NKT + 32) * 512), a0);
        a1 = MFMA16(xv0, *(const half8*)(bp + (size_t)(1 * NKT + 32) * 512), a1);
        a2 = MFMA16(xv0, *(const half8*)(bp + (size_t)(2 * NKT + 32) * 512), a2);
        a3 = MFMA16(xv0, *(const half8*)(bp + (size_t)(3 * NKT + 32) * 512), a3);
        a0 = MFMA16(xv1, *(const half8*)(bp + (size_t)(0 * NKT + 33) * 512), a0);
        a1 = MFMA16(xv1, *(const half8*)(bp + (size_t)(1 * NKT + 33) * 512), a1);
        a2 = MFMA16(xv1, *(const half8*)(bp + (size_t)(2 * NKT + 33) * 512), a2);
        a3 = MFMA16(xv1, *(const half8*)(bp + (size_t)(3 * NKT + 33) * 512), a3);
      }

      // ---- h part: K=1024 over 4 chunks (kt 8q..8q+7 gated by go word q) ----
      const half_t* ap = habase + (size_t)t * BUFV;
      if (t == 0) {
        #pragma unroll 8
        for (int kt = 0; kt < 32; ++kt) GKT(kt)
      } else {
        const unsigned tt = (unsigned)t;
        while (g0 < tt) {
          __builtin_amdgcn_s_sleep(2);
          const unsigned long long v01 = __hip_atomic_load(
              (const unsigned long long*)goline, __ATOMIC_RELAXED,
              __HIP_MEMORY_SCOPE_AGENT);
          const unsigned long long v23 = __hip_atomic_load(
              (const unsigned long long*)(goline + 2), __ATOMIC_RELAXED,
              __HIP_MEMORY_SCOPE_AGENT);
          g0 = (unsigned)v01; g1 = (unsigned)(v01 >> 32);
          g2 = (unsigned)v23; g3 = (unsigned)(v23 >> 32);
        }
        asm volatile("" ::: "memory");
        if (g1 >= tt && g2 >= tt && g3 >= tt) {
          // fast path: identical codegen/order to the straight loop
          #pragma unroll 8
          for (int kt = 0; kt < 32; ++kt) GKT(kt)
        } else {
          // slow path: overlap ready chunks with the stragglers
          #pragma unroll
          for (int k2 = 0; k2 < 8; ++k2) GKT(k2)
          #pragma unroll
          for (int q = 1; q < 4; ++q) {
            unsigned gq = (q == 1) ? g1 : (q == 2) ? g2 : g3;
            while (gq < tt) {
              __builtin_amdgcn_s_sleep(2);
              gq = __hip_atomic_load(goline + q, __ATOMIC_RELAXED,
                                     __HIP_MEMORY_SCOPE_AGENT);
            }
            asm volatile("" ::: "memory");
            #pragma unroll
            for (int k2 = 0; k2 < 8; ++k2) GKT(q * 8 + k2)
          }
        }
      }

      // ---- intra-wave pre-activation exchange (no barrier) ----
      #pragma unroll
      for (int r = 0; r < 4; ++r) {
        const int rl = (kq * 4 + r) * PRE_STRIDE;
        pw[rl + rn] = a0[r];
        pw[rl + 16 + rn] = a1[r];
        pw[rl + 32 + rn] = a2[r];
        pw[rl + 48 + rn] = a3[r];
      }

      // ---- cell update (c in registers) ----
      const float4v pg0 = *(const float4v*)(pw + crow * PRE_STRIDE + hl);
      const float4v pg1 = *(const float4v*)(pw + crow * PRE_STRIDE + 16 + hl);
      const float4v pg2 = *(const float4v*)(pw + crow * PRE_STRIDE + 32 + hl);
      const float4v pg3 = *(const float4v*)(pw + crow * PRE_STRIDE + 48 + hl);
      half4 hnew;
      #pragma unroll
      for (int jj = 0; jj < 4; ++jj) {
        const float ig = pg0[jj] + bsum[0][jj];
        const float fg = pg1[jj] + bsum[1][jj];
        const float gg = pg2[jj] + bsum[2][jj];
        const float og = pg3[jj] + bsum[3][jj];
        const float is = 1.f / (1.f + __expf(-ig));
        const float fs = 1.f / (1.f + __expf(-fg));
        const float os = 1.f / (1.f + __expf(-og));
        const float gt = tanhf(gg);
        const float cn = fs * creg[jj] + is * gt;
        creg[jj] = cn;
        hnew[jj] = (half_t)(os * tanhf(cn));
      }
      astore8(g_hA + (size_t)(t + 1) * BUFV + hoff, hnew);

      // ---- release: own rows at LLC, publish own per-wave u16 slot ----
      __builtin_amdgcn_s_waitcnt(0);
      if (lane == 0)
        __hip_atomic_store(myslot, (unsigned short)(t + 1), __ATOMIC_RELAXED,
                           __HIP_MEMORY_SCOPE_AGENT);
    }

  } else if (jtile < 32) {
    // ================= dense1 head waves (4-way K split) =================
    const int u = wave - 4;             // 0..3: ktiles u*8 .. u*8+7 (chunk u)
    const int rb = jtile >> 3, cb = jtile & 7;
    const int mt = mtile * 4 + rb;
    const half_t* hb = g_hA + ((size_t)mt * 32 + u * 8) * 512 + lane * 8;
    const half_t* bb = Wd_f + ((size_t)cb * 32 + u * 8) * 512 + lane * 8;
    const unsigned int* myg = goline + u;   // this chunk's go word

    for (int s = 1; s <= SS; ++s) {
      while (__hip_atomic_load(myg, __ATOMIC_RELAXED,
                               __HIP_MEMORY_SCOPE_AGENT) < (unsigned)s)
        __builtin_amdgcn_s_sleep(2);
      asm volatile("" ::: "memory");

      const half_t* ap = hb + (size_t)s * BUFV;
      float4v acc = {0.f, 0.f, 0.f, 0.f};
      #pragma unroll
      for (int kt = 0; kt < 8; ++kt)
        acc = MFMA16(*(const half8*)(ap + (size_t)kt * 512),
                     *(const half8*)(bb + (size_t)kt * 512), acc);

      if (u) {
        // back-pressure: wave 4 must have consumed step s-1 partials
        if (s > 1)
          while (__hip_atomic_load(&flg[4], __ATOMIC_ACQUIRE,
                                   __HIP_MEMORY_SCOPE_WORKGROUP) <
                 (unsigned)(s - 1))
            __builtin_amdgcn_s_sleep(1);
        *(float4v*)(dp + ((size_t)(u - 1) * 64 + lane) * 4) = acc;
        __hip_atomic_store(&flg[u - 1], (unsigned)s, __ATOMIC_RELEASE,
                           __HIP_MEMORY_SCOPE_WORKGROUP);
      } else {
        for (;;) {
          const unsigned f0 = __hip_atomic_load(&flg[0], __ATOMIC_ACQUIRE,
                                                __HIP_MEMORY_SCOPE_WORKGROUP);
          const unsigned f1 = __hip_atomic_load(&flg[1], __ATOMIC_ACQUIRE,
                                                __HIP_MEMORY_SCOPE_WORKGROUP);
          const unsigned f2 = __hip_atomic_load(&flg[2], __ATOMIC_ACQUIRE,
                                                __HIP_MEMORY_SCOPE_WORKGROUP);
          if (f0 >= (unsigned)s && f1 >= (unsigned)s && f2 >= (unsigned)s) break;
          __builtin_amdgcn_s_sleep(1);
        }
        asm volatile("" ::: "memory");
        #pragma unroll
        for (int i = 0; i < 3; ++i) {
          const float4v p = *(const float4v*)(dp + ((size_t)i * 64 + lane) * 4);
          #pragma unroll
          for (int r = 0; r < 4; ++r) acc[r] += p[r];
        }
        __hip_atomic_store(&flg[4], (unsigned)s, __ATOMIC_RELEASE,
                           __HIP_MEMORY_SCOPE_WORKGROUP);  // ack producers
        const int dcol = cb * 16 + rn;
        const float bv = bd[dcol];
        half_t* db = g_dbuf + (((size_t)(s - 1) * 16 + mt) * 16) * HEADD + dcol;
        #pragma unroll
        for (int r = 0; r < 4; ++r)
          astore2(db + (size_t)(kq * 4 + r) * HEADD,
                  (half_t)fmaxf(acc[r] + bv, 0.f));
        __builtin_amdgcn_s_waitcnt(0);
        if (lane == 0)
          __hip_atomic_fetch_add(dcnt, 1u, __ATOMIC_RELAXED,
                                 __HIP_MEMORY_SCOPE_AGENT);
      }
    }

  } else if (jtile < 48 && wave == 4) {
    // ================= dense2 head wave =================
    const int task = jtile - 32;
    const int rb = task >> 2, cb2 = task & 3;
    const int mt = mtile * 4 + rb;
    const int m0 = mtile * 64;
    const half_t* bp2 = Wd2_f + (size_t)cb2 * 4 * 512 + lane * 8;
    for (int d = 0; d < SS; ++d) {
      if (lane == 0) {
        const unsigned tgt = 32u * (unsigned)(d + 1);
        while (__hip_atomic_load(dcnt, __ATOMIC_RELAXED,
                                 __HIP_MEMORY_SCOPE_AGENT) < tgt)
          __builtin_amdgcn_s_sleep(16);
      }
      asm volatile("" ::: "memory");
      const half_t* ap = g_dbuf + (((size_t)d * 16 + mt) * 16) * HEADD;
      float4v acc = {0.f, 0.f, 0.f, 0.f};
      #pragma unroll
      for (int kt = 0; kt < 4; ++kt) {
        const half8 af =
            *(const half8*)(ap + (size_t)rn * HEADD + kt * 32 + kq * 8);
        acc = MFMA16(af, *(const half8*)(bp2 + (size_t)kt * 512), acc);
      }
      const int ocol = cb2 * 16 + rn;
      const float bv = bd2[ocol];
      #pragma unroll
      for (int r = 0; r < 4; ++r) {
        const int row = m0 + rb * 16 + kq * 4 + r;
        out[(size_t)row * (SS * OUTD) + (size_t)d * OUTD + ocol] = acc[r] + bv;
      }
    }

  } else if (jtile == 63 && wave == 5) {
    // ========= aggregator wave: per-chunk running-min broadcaster =========
    // lane l gathers jtile l's slot line; 16-lane-group min = chunk (l>>4)
    // progress; lane l publishes it to copy (l&15), word (l>>4). Plain
    // stores, store-if-changed; no RMW anywhere.
    const unsigned long long* pollp =
        (const unsigned long long*)(g_sync + ((size_t)(mtile * 64 + lane)) * 32);
    unsigned int* myg = go_base + (lane & 15) * 32 + (lane >> 4);
    unsigned prev = 0;
    for (;;) {
      const unsigned long long v = __hip_atomic_load(
          pollp, __ATOMIC_RELAXED, __HIP_MEMORY_SCOPE_AGENT);
      const unsigned f0 = (unsigned)(v & 0xffffu);
      const unsigned f1 = (unsigned)((v >> 16) & 0xffffu);
      const unsigned f2 = (unsigned)((v >> 32) & 0xffffu);
      const unsigned f3 = (unsigned)(v >> 48);
      unsigned m0v = f0 < f1 ? f0 : f1;
      const unsigned m1v = f2 < f3 ? f2 : f3;
      unsigned m = m0v < m1v ? m0v : m1v;
      #pragma unroll
      for (int off = 1; off < 16; off <<= 1) {
        const unsigned o = (unsigned)__shfl_xor((int)m, off);
        m = o < m ? o : m;
      }
      if (m > prev) {
        __hip_atomic_store(myg, m, __ATOMIC_RELAXED, __HIP_MEMORY_SCOPE_AGENT);
        prev = m;
      }
      if (__all((int)(m >= (unsigned)SS))) break;
    }
    __builtin_amdgcn_s_waitcnt(0);
  }
}

extern "C" void kernel_launch(void* const* d_in, const int* in_sizes, int n_in,
                              void* d_out, int out_size, void* d_ws, size_t ws_size,
                              hipStream_t stream) {
  const float* x        = (const float*)d_in[0];
  const float* W_ih     = (const float*)d_in[1];
  const float* b_ih     = (const float*)d_in[2];
  const float* W_hh     = (const float*)d_in[3];
  const float* b_hh     = (const float*)d_in[4];
  const float* W_dense  = (const float*)d_in[5];
  const float* b_dense  = (const float*)d_in[6];
  const float* W_dense2 = (const float*)d_in[7];
  const float* b_dense2 = (const float*)d_in[8];
  float* out = (float*)d_out;

  char* p = (char*)d_ws;
  half_t* xA    = (half_t*)p; p += (size_t)SS * 16 * 1024 * 2;  // 16.8 MB
  half_t* Wd_f  = (half_t*)p; p += (size_t)8 * 32 * 512 * 2;    // 256 KB
  half_t* Wd2_f = (half_t*)p; p += (size_t)4 * 4 * 512 * 2;     // 16 KB

  init_state<<<256, 256, 0, stream>>>();
  pack_x<<<dim3(SS, 16), 256, 0, stream>>>(x, xA);
  frag_pack<<<HEADD / 16, 256, 0, stream>>>(W_dense, Wd_f, HH);
  frag_pack<<<OUTD / 16, 256, 0, stream>>>(W_dense2, Wd2_f, HEADD);

  hipFuncSetAttribute((const void*)lstm_persistent,
                      hipFuncAttributeMaxDynamicSharedMemorySize, SMEM_BYTES);
  void* args[] = {(void*)&W_hh, (void*)&W_ih, (void*)&b_ih, (void*)&b_hh,
                  (void*)&xA, (void*)&Wd_f, (void*)&b_dense,
                  (void*)&Wd2_f, (void*)&b_dense2, (void*)&out};
  hipLaunchCooperativeKernel((void*)lstm_persistent, dim3(256), dim3(512),
                             args, SMEM_BYTES, stream);
}

// Round 5
// 4387.583 us; speedup vs baseline: 1.3572x; 1.3572x over previous
//
#include <hip/hip_runtime.h>

typedef _Float16 half_t;
typedef _Float16 half8 __attribute__((ext_vector_type(8)));
typedef _Float16 half4 __attribute__((ext_vector_type(4)));
typedef float float4v __attribute__((ext_vector_type(4)));

#define BB    256
#define SS    512
#define IND   64
#define HH    1024
#define HEADD 128
#define OUTD  64
#define NKT   34                      // K tiles of 32: 32 (h) + 2 (x)
#define WLDS_HALVES (4 * NKT * 512)   // 69632 halves = 139264 B
#define PRE_STRIDE 68                 // padded float stride
#define DP_OFF   (WLDS_HALVES * 2 + 4 * 16 * PRE_STRIDE * 4)  // 156672
#define FLAG_OFF (DP_OFF + 3 * 64 * 4 * 4)                    // 159744
#define SMEM_BYTES (FLAG_OFF + 32)                            // 159776 B
#define BUFV (BB * HH)                // halves per h step-buffer (512 KB)
// g_sync layout (words):
//  [(mtile*64+jtile)*32]         slot line: 4 u16 per-gate-wave flags
//  [8192 + mtile*512 + copy*32]  go lines (16 copies per mtile)
//  [10240 + mtile*32]            dcnt (dense1 completion counter)
#define GO_OFF   8192
#define DCNT_OFF 10240
#define SYNC_WORDS 10368

#define MFMA16(a, b, acc) __builtin_amdgcn_mfma_f32_16x16x32_f16(a, b, acc, 0, 0, 0)

// Rotating write-once state in device globals: every address is written at
// most once per dispatch before being read -> plain cached loads are
// coherence-safe (producer sc-stores land at LLC; consumer caches are
// invalidated at dispatch start and never touch these lines beforehand).
__device__ half_t g_hA[(size_t)(SS + 1) * BUFV];          // ~263 MB
__device__ half_t g_dbuf[(size_t)SS * 256 * HEADD];       // ~33.5 MB
__device__ unsigned int g_sync[SYNC_WORDS];

__device__ __forceinline__ void astore8(half_t* p, half4 v) {
  union { half4 h; unsigned long long u; } r; r.h = v;
  __hip_atomic_store((unsigned long long*)p, r.u, __ATOMIC_RELAXED,
                     __HIP_MEMORY_SCOPE_AGENT);
}
__device__ __forceinline__ void astore2(half_t* p, half_t v) {
  union { half_t h; unsigned short u; } r; r.h = v;
  __hip_atomic_store((unsigned short*)p, r.u, __ATOMIC_RELAXED,
                     __HIP_MEMORY_SCOPE_AGENT);
}

// ---------- prologue ----------

__global__ __launch_bounds__(256) void init_state() {
  const size_t i = (size_t)blockIdx.x * 256 + threadIdx.x;  // 65536 threads
  *(unsigned long long*)(g_hA + i * 4) = 0ULL;              // zero buffer 0
  if (blockIdx.x == 0)
    for (int j = threadIdx.x; j < SYNC_WORDS; j += 256) g_sync[j] = 0;
}

// x[B][S][IN] fp32 -> xA[t][mt][kt][lane][8] fp16 (A-fragment order per step)
__global__ __launch_bounds__(256) void pack_x(const float* __restrict__ x,
                                              half_t* __restrict__ xA) {
  const int t = blockIdx.x, mt = blockIdx.y;
  const int tid = threadIdx.x;
  const int kt = tid >> 7;
  const int lane = (tid >> 1) & 63;
  const int jh = (tid & 1) * 4;
  const int row = mt * 16 + (lane & 15);
  const int k = kt * 32 + (lane >> 4) * 8 + jh;
  const float* s = x + (size_t)row * SS * IND + (size_t)t * IND + k;
  half_t* d = xA + (((size_t)t * 16 + mt) * 2 + kt) * 512 + lane * 8 + jh;
  d[0] = (half_t)s[0]; d[1] = (half_t)s[1];
  d[2] = (half_t)s[2]; d[3] = (half_t)s[3];
}

// row-major fp32 [N][K] -> fp16 B-fragment order [cb][kt][lane][8]
__global__ __launch_bounds__(256) void frag_pack(const float* __restrict__ src,
                                                 half_t* __restrict__ dst, int K) {
  const int cb = blockIdx.x;
  const int tid = threadIdx.x;
  const int lane = tid & 63;
  const int u = tid >> 6;
  const int nkt = K >> 5;
  const int row = cb * 16 + (lane & 15);
  for (int kt = u; kt < nkt; kt += 4) {
    const int k = kt * 32 + (lane >> 4) * 8;
    const float* s = src + (size_t)row * K + k;
    half8 h;
    #pragma unroll
    for (int j = 0; j < 8; ++j) h[j] = (half_t)s[j];
    *(half8*)(dst + ((size_t)cb * nkt + kt) * 512 + lane * 8) = h;
  }
}

// ---------- persistent LSTM kernel (cooperative, 256 WGs = 1/CU) ----------
// 512 threads/WG. Waves 0..3: recurrence (gate g = wave), no barriers in the
// steady state; per-wave u16 release flags. Wave 5 of jtile 63 = aggregator
// (2-hop sync, proven traffic profile). Waves 4..7: dense head paced off an
// LDS step flag -> the head never touches the recurrence critical path.
// XCD clustering: with round-robin bid->XCD (bid&7), each mtile's 64 WGs
// occupy exactly 2 XCDs, so each freshly-written h line is LLC-fetched 2x
// (not 8x) and most consumer h-reads are same-XCD L2 hits.
__global__ __launch_bounds__(512, 2) void lstm_persistent(
    const float* __restrict__ W_hh, const float* __restrict__ W_ih,
    const float* __restrict__ b_ih, const float* __restrict__ b_hh,
    const half_t* __restrict__ xA, const half_t* __restrict__ Wd_f,
    const float* __restrict__ bd, const half_t* __restrict__ Wd2_f,
    const float* __restrict__ bd2, float* __restrict__ out) {
  extern __shared__ char smem[];
  half_t* Wlds = (half_t*)smem;
  float* pre = (float*)(smem + (size_t)WLDS_HALVES * 2);
  float* dp = (float*)(smem + DP_OFF);          // dense1 partials [3][64][4]
  unsigned* flg = (unsigned*)(smem + FLAG_OFF); // [0..2]=dflag [3]=hstep [4]=ack

  const int bid = blockIdx.x;
  const int xcd = bid & 7;            // round-robin XCD assumption (m09)
  const int mtile = xcd >> 1;         // 0..3  -> XCD pair {2m, 2m+1}
  const int jtile = ((bid >> 3) << 1) | (xcd & 1);  // 0..63, unique per mtile
  const int j0 = jtile * 16;
  const int tid = threadIdx.x;
  const int wave = tid >> 6;
  const int lane = tid & 63;
  const int rn = lane & 15;
  const int kq = lane >> 4;

  // ---- stage W gate-slice into LDS in B-fragment order (8 waves) ----
  {
    const int g = wave & 3;
    const int row = g * HH + j0 + rn;
    for (int kt = (wave >> 2); kt < NKT; kt += 2) {
      const int k = kt * 32 + kq * 8;
      const float* s = (k < HH) ? (W_hh + (size_t)row * HH + k)
                                : (W_ih + (size_t)row * IND + (k - HH));
      half8 hv;
      #pragma unroll
      for (int j = 0; j < 8; ++j) hv[j] = (half_t)s[j];
      *(half8*)(Wlds + ((size_t)g * NKT + kt) * 512 + lane * 8) = hv;
    }
  }
  if (tid < 8) flg[tid] = 0;
  __syncthreads();   // only barrier in the kernel

  unsigned short* slotp =
      (unsigned short*)(g_sync + ((size_t)(mtile * 64 + jtile)) * 32);
  unsigned int* go_base = g_sync + GO_OFF + mtile * 512;
  const unsigned int* gop = go_base + (jtile & 15) * 32;
  unsigned int* dcnt = g_sync + DCNT_OFF + mtile * 32;

  if (wave < 4) {
    // ================= recurrence (gate) waves =================
    const int crow = lane >> 2;         // 0..15 row within wave's block
    const int hl = (lane & 3) * 4;      // col base 0,4,8,12
    float bsum[4][4];
    #pragma unroll
    for (int g = 0; g < 4; ++g) {
      const float4v bi = *(const float4v*)(b_ih + g * HH + j0 + hl);
      const float4v bh = *(const float4v*)(b_hh + g * HH + j0 + hl);
      #pragma unroll
      for (int j = 0; j < 4; ++j) bsum[g][j] = bi[j] + bh[j];
    }
    float4v creg = {0.f, 0.f, 0.f, 0.f};

    const int mtA = mtile * 4 + wave;   // wave's 16-row block (global mt 0..15)
    float* pw = pre + wave * (16 * PRE_STRIDE);

    const int col_s = j0 + hl;
    const int ktw = col_s >> 5;
    const int kqw = (col_s & 31) >> 3;
    const int jw = col_s & 7;
    const size_t hoff =
        (((size_t)(mtA * 32 + ktw)) * 64 + kqw * 16 + crow) * 8 + jw;

    const half_t* habase = g_hA + ((size_t)mtA * 32) * 512 + lane * 8;
    const half_t* bp = Wlds + lane * 8;
    unsigned short* myslot = slotp + wave;

    for (int t = 0; t < SS; ++t) {
      float4v a0 = {0.f, 0.f, 0.f, 0.f}, a1 = {0.f, 0.f, 0.f, 0.f};
      float4v a2 = {0.f, 0.f, 0.f, 0.f}, a3 = {0.f, 0.f, 0.f, 0.f};

      // ---- x part first: independent of h_t, hides work under the wait ----
      const half_t* xp = xA + (((size_t)t * 16 + mtA) * 2) * 512 + lane * 8;
      {
        const half8 xv0 = *(const half8*)xp;
        const half8 xv1 = *(const half8*)(xp + 512);
        a0 = MFMA16(xv0, *(const half8*)(bp + (size_t)(0 * NKT + 32) * 512), a0);
        a1 = MFMA16(xv0, *(const half8*)(bp + (size_t)(1 * NKT + 32) * 512), a1);
        a2 = MFMA16(xv0, *(const half8*)(bp + (size_t)(2 * NKT + 32) * 512), a2);
        a3 = MFMA16(xv0, *(const half8*)(bp + (size_t)(3 * NKT + 32) * 512), a3);
        a0 = MFMA16(xv1, *(const half8*)(bp + (size_t)(0 * NKT + 33) * 512), a0);
        a1 = MFMA16(xv1, *(const half8*)(bp + (size_t)(1 * NKT + 33) * 512), a1);
        a2 = MFMA16(xv1, *(const half8*)(bp + (size_t)(2 * NKT + 33) * 512), a2);
        a3 = MFMA16(xv1, *(const half8*)(bp + (size_t)(3 * NKT + 33) * 512), a3);
      }

      // ---- acquire: poll this WG's go line (1 coalesced LLC access/poll) ----
      if (t >= 1) {
        const unsigned tt = (unsigned)t;
        while (__hip_atomic_load(gop, __ATOMIC_RELAXED,
                                 __HIP_MEMORY_SCOPE_AGENT) < tt)
          __builtin_amdgcn_s_sleep(2);
        asm volatile("" ::: "memory");
        if (wave == 0 && lane == 0)   // relay to head waves (LDS, monotonic)
          __hip_atomic_store(&flg[3], tt, __ATOMIC_RELEASE,
                             __HIP_MEMORY_SCOPE_WORKGROUP);
      }

      // ---- h part: wave computes 16 rows x 64 gate-cols, K=1024 ----
      const half_t* ap = habase + (size_t)t * BUFV;
      #pragma unroll 8
      for (int kt = 0; kt < 32; ++kt) {
        const half8 av = *(const half8*)(ap + (size_t)kt * 512);
        a0 = MFMA16(av, *(const half8*)(bp + (size_t)(0 * NKT + kt) * 512), a0);
        a1 = MFMA16(av, *(const half8*)(bp + (size_t)(1 * NKT + kt) * 512), a1);
        a2 = MFMA16(av, *(const half8*)(bp + (size_t)(2 * NKT + kt) * 512), a2);
        a3 = MFMA16(av, *(const half8*)(bp + (size_t)(3 * NKT + kt) * 512), a3);
      }

      // ---- intra-wave pre-activation exchange (no barrier) ----
      #pragma unroll
      for (int r = 0; r < 4; ++r) {
        const int rl = (kq * 4 + r) * PRE_STRIDE;
        pw[rl + rn] = a0[r];
        pw[rl + 16 + rn] = a1[r];
        pw[rl + 32 + rn] = a2[r];
        pw[rl + 48 + rn] = a3[r];
      }

      // ---- cell update (c in registers) ----
      const float4v pg0 = *(const float4v*)(pw + crow * PRE_STRIDE + hl);
      const float4v pg1 = *(const float4v*)(pw + crow * PRE_STRIDE + 16 + hl);
      const float4v pg2 = *(const float4v*)(pw + crow * PRE_STRIDE + 32 + hl);
      const float4v pg3 = *(const float4v*)(pw + crow * PRE_STRIDE + 48 + hl);
      half4 hnew;
      #pragma unroll
      for (int jj = 0; jj < 4; ++jj) {
        const float ig = pg0[jj] + bsum[0][jj];
        const float fg = pg1[jj] + bsum[1][jj];
        const float gg = pg2[jj] + bsum[2][jj];
        const float og = pg3[jj] + bsum[3][jj];
        const float is = 1.f / (1.f + __expf(-ig));
        const float fs = 1.f / (1.f + __expf(-fg));
        const float os = 1.f / (1.f + __expf(-og));
        const float gt = tanhf(gg);
        const float cn = fs * creg[jj] + is * gt;
        creg[jj] = cn;
        hnew[jj] = (half_t)(os * tanhf(cn));
      }
      astore8(g_hA + (size_t)(t + 1) * BUFV + hoff, hnew);

      // ---- release: own rows at LLC, publish own per-wave u16 slot ----
      __builtin_amdgcn_s_waitcnt(0);
      if (lane == 0)
        __hip_atomic_store(myslot, (unsigned short)(t + 1), __ATOMIC_RELAXED,
                           __HIP_MEMORY_SCOPE_AGENT);
    }

    // final relay so head waves can process h_SS
    if (wave == 0) {
      while (__hip_atomic_load(gop, __ATOMIC_RELAXED,
                               __HIP_MEMORY_SCOPE_AGENT) < (unsigned)SS)
        __builtin_amdgcn_s_sleep(2);
      asm volatile("" ::: "memory");
      if (lane == 0)
        __hip_atomic_store(&flg[3], (unsigned)SS, __ATOMIC_RELEASE,
                           __HIP_MEMORY_SCOPE_WORKGROUP);
    }

  } else if (jtile < 32) {
    // ================= dense1 head waves (4-way K split) =================
    const int u = wave - 4;             // 0..3: ktiles u*8 .. u*8+7
    const int rb = jtile >> 3, cb = jtile & 7;
    const int mt = mtile * 4 + rb;
    const half_t* hb = g_hA + ((size_t)mt * 32 + u * 8) * 512 + lane * 8;
    const half_t* bb = Wd_f + ((size_t)cb * 32 + u * 8) * 512 + lane * 8;

    for (int s = 1; s <= SS; ++s) {
      while (__hip_atomic_load(&flg[3], __ATOMIC_ACQUIRE,
                               __HIP_MEMORY_SCOPE_WORKGROUP) < (unsigned)s)
        __builtin_amdgcn_s_sleep(2);
      asm volatile("" ::: "memory");

      const half_t* ap = hb + (size_t)s * BUFV;
      float4v acc = {0.f, 0.f, 0.f, 0.f};
      #pragma unroll
      for (int kt = 0; kt < 8; ++kt)
        acc = MFMA16(*(const half8*)(ap + (size_t)kt * 512),
                     *(const half8*)(bb + (size_t)kt * 512), acc);

      if (u) {
        // back-pressure: wave 4 must have consumed step s-1 partials
        if (s > 1)
          while (__hip_atomic_load(&flg[4], __ATOMIC_ACQUIRE,
                                   __HIP_MEMORY_SCOPE_WORKGROUP) <
                 (unsigned)(s - 1))
            __builtin_amdgcn_s_sleep(1);
        *(float4v*)(dp + ((size_t)(u - 1) * 64 + lane) * 4) = acc;
        __hip_atomic_store(&flg[u - 1], (unsigned)s, __ATOMIC_RELEASE,
                           __HIP_MEMORY_SCOPE_WORKGROUP);
      } else {
        for (;;) {
          const unsigned f0 = __hip_atomic_load(&flg[0], __ATOMIC_ACQUIRE,
                                                __HIP_MEMORY_SCOPE_WORKGROUP);
          const unsigned f1 = __hip_atomic_load(&flg[1], __ATOMIC_ACQUIRE,
                                                __HIP_MEMORY_SCOPE_WORKGROUP);
          const unsigned f2 = __hip_atomic_load(&flg[2], __ATOMIC_ACQUIRE,
                                                __HIP_MEMORY_SCOPE_WORKGROUP);
          if (f0 >= (unsigned)s && f1 >= (unsigned)s && f2 >= (unsigned)s) break;
          __builtin_amdgcn_s_sleep(1);
        }
        asm volatile("" ::: "memory");
        #pragma unroll
        for (int i = 0; i < 3; ++i) {
          const float4v p = *(const float4v*)(dp + ((size_t)i * 64 + lane) * 4);
          #pragma unroll
          for (int r = 0; r < 4; ++r) acc[r] += p[r];
        }
        __hip_atomic_store(&flg[4], (unsigned)s, __ATOMIC_RELEASE,
                           __HIP_MEMORY_SCOPE_WORKGROUP);  // ack producers
        const int dcol = cb * 16 + rn;
        const float bv = bd[dcol];
        half_t* db = g_dbuf + (((size_t)(s - 1) * 16 + mt) * 16) * HEADD + dcol;
        #pragma unroll
        for (int r = 0; r < 4; ++r)
          astore2(db + (size_t)(kq * 4 + r) * HEADD,
                  (half_t)fmaxf(acc[r] + bv, 0.f));
        __builtin_amdgcn_s_waitcnt(0);
        if (lane == 0)
          __hip_atomic_fetch_add(dcnt, 1u, __ATOMIC_RELAXED,
                                 __HIP_MEMORY_SCOPE_AGENT);
      }
    }

  } else if (jtile < 48 && wave == 4) {
    // ================= dense2 head wave =================
    const int task = jtile - 32;
    const int rb = task >> 2, cb2 = task & 3;
    const int mt = mtile * 4 + rb;
    const int m0 = mtile * 64;
    const half_t* bp2 = Wd2_f + (size_t)cb2 * 4 * 512 + lane * 8;
    for (int d = 0; d < SS; ++d) {
      if (lane == 0) {
        const unsigned tgt = 32u * (unsigned)(d + 1);
        while (__hip_atomic_load(dcnt, __ATOMIC_RELAXED,
                                 __HIP_MEMORY_SCOPE_AGENT) < tgt)
          __builtin_amdgcn_s_sleep(16);
      }
      asm volatile("" ::: "memory");
      const half_t* ap = g_dbuf + (((size_t)d * 16 + mt) * 16) * HEADD;
      float4v acc = {0.f, 0.f, 0.f, 0.f};
      #pragma unroll
      for (int kt = 0; kt < 4; ++kt) {
        const half8 af =
            *(const half8*)(ap + (size_t)rn * HEADD + kt * 32 + kq * 8);
        acc = MFMA16(af, *(const half8*)(bp2 + (size_t)kt * 512), acc);
      }
      const int ocol = cb2 * 16 + rn;
      const float bv = bd2[ocol];
      #pragma unroll
      for (int r = 0; r < 4; ++r) {
        const int row = m0 + rb * 16 + kq * 4 + r;
        out[(size_t)row * (SS * OUTD) + (size_t)d * OUTD + ocol] = acc[r] + bv;
      }
    }

  } else if (jtile == 63 && wave == 5) {
    // ================= aggregator wave (one per mtile) =================
    const unsigned long long* pollp =
        (const unsigned long long*)(g_sync + ((size_t)(mtile * 64 + lane)) * 32);
    for (int t = 1; t <= SS; ++t) {
      const unsigned tt = (unsigned)t;
      for (;;) {
        const unsigned long long v = __hip_atomic_load(
            pollp, __ATOMIC_RELAXED, __HIP_MEMORY_SCOPE_AGENT);
        const unsigned f0 = (unsigned)(v & 0xffffu);
        const unsigned f1 = (unsigned)((v >> 16) & 0xffffu);
        const unsigned f2 = (unsigned)((v >> 32) & 0xffffu);
        const unsigned f3 = (unsigned)(v >> 48);
        if (__all((int)(f0 >= tt && f1 >= tt && f2 >= tt && f3 >= tt))) break;
        __builtin_amdgcn_s_sleep(2);
      }
      asm volatile("" ::: "memory");
      if (lane < 16)
        __hip_atomic_store(go_base + lane * 32, tt, __ATOMIC_RELAXED,
                           __HIP_MEMORY_SCOPE_AGENT);
    }
  }
}

extern "C" void kernel_launch(void* const* d_in, const int* in_sizes, int n_in,
                              void* d_out, int out_size, void* d_ws, size_t ws_size,
                              hipStream_t stream) {
  const float* x        = (const float*)d_in[0];
  const float* W_ih     = (const float*)d_in[1];
  const float* b_ih     = (const float*)d_in[2];
  const float* W_hh     = (const float*)d_in[3];
  const float* b_hh     = (const float*)d_in[4];
  const float* W_dense  = (const float*)d_in[5];
  const float* b_dense  = (const float*)d_in[6];
  const float* W_dense2 = (const float*)d_in[7];
  const float* b_dense2 = (const float*)d_in[8];
  float* out = (float*)d_out;

  char* p = (char*)d_ws;
  half_t* xA    = (half_t*)p; p += (size_t)SS * 16 * 1024 * 2;  // 16.8 MB
  half_t* Wd_f  = (half_t*)p; p += (size_t)8 * 32 * 512 * 2;    // 256 KB
  half_t* Wd2_f = (half_t*)p; p += (size_t)4 * 4 * 512 * 2;     // 16 KB

  init_state<<<256, 256, 0, stream>>>();
  pack_x<<<dim3(SS, 16), 256, 0, stream>>>(x, xA);
  frag_pack<<<HEADD / 16, 256, 0, stream>>>(W_dense, Wd_f, HH);
  frag_pack<<<OUTD / 16, 256, 0, stream>>>(W_dense2, Wd2_f, HEADD);

  hipFuncSetAttribute((const void*)lstm_persistent,
                      hipFuncAttributeMaxDynamicSharedMemorySize, SMEM_BYTES);
  void* args[] = {(void*)&W_hh, (void*)&W_ih, (void*)&b_ih, (void*)&b_hh,
                  (void*)&xA, (void*)&Wd_f, (void*)&b_dense,
                  (void*)&Wd2_f, (void*)&b_dense2, (void*)&out};
  hipLaunchCooperativeKernel((void*)lstm_persistent, dim3(256), dim3(512),
                             args, SMEM_BYTES, stream);
}

// Round 6
// 4263.006 us; speedup vs baseline: 1.3968x; 1.0292x over previous
//
#include <hip/hip_runtime.h>

typedef _Float16 half_t;
typedef _Float16 half8 __attribute__((ext_vector_type(8)));
typedef _Float16 half4 __attribute__((ext_vector_type(4)));
typedef float float4v __attribute__((ext_vector_type(4)));

#define BB    256
#define SS    512
#define IND   64
#define HH    1024
#define HEADD 128
#define OUTD  64
#define NKT   34                      // K tiles of 32: 32 (h) + 2 (x)
#define WLDS_HALVES (4 * NKT * 512)   // 69632 halves = 139264 B
#define PRE_STRIDE 68                 // padded float stride
#define DP_OFF   (WLDS_HALVES * 2 + 4 * 16 * PRE_STRIDE * 4)  // 156672
#define FLAG_OFF (DP_OFF + 3 * 64 * 4 * 4)                    // 159744
#define SMEM_BYTES (FLAG_OFF + 32)                            // 159776 B
#define BUFV (BB * HH)                // halves per h step-buffer (512 KB)
// g_sync layout (words):
//  [(mtile*64+jtile)*32]         slot line: 4 u16 per-gate-wave flags
//  [8192 + mtile*512 + copy*32]  go lines (16 copies per mtile)
//  [10240 + mtile*32]            dcnt (dense1 completion counter)
#define GO_OFF   8192
#define DCNT_OFF 10240
#define SYNC_WORDS 10368

#define MFMA16(a, b, acc) __builtin_amdgcn_mfma_f32_16x16x32_f16(a, b, acc, 0, 0, 0)

// Rotating write-once state in device globals: every address is written at
// most once per dispatch before being read -> plain cached loads are
// coherence-safe (producer sc-stores land at LLC; consumer caches are
// invalidated at dispatch start and never touch these lines beforehand).
__device__ half_t g_hA[(size_t)(SS + 1) * BUFV];          // ~263 MB
__device__ half_t g_dbuf[(size_t)SS * 256 * HEADD];       // ~33.5 MB
__device__ unsigned int g_sync[SYNC_WORDS];

__device__ __forceinline__ void astore8(half_t* p, half4 v) {
  union { half4 h; unsigned long long u; } r; r.h = v;
  __hip_atomic_store((unsigned long long*)p, r.u, __ATOMIC_RELAXED,
                     __HIP_MEMORY_SCOPE_AGENT);
}
__device__ __forceinline__ void astore2(half_t* p, half_t v) {
  union { half_t h; unsigned short u; } r; r.h = v;
  __hip_atomic_store((unsigned short*)p, r.u, __ATOMIC_RELAXED,
                     __HIP_MEMORY_SCOPE_AGENT);
}

// ---------- prologue ----------

__global__ __launch_bounds__(256) void init_state() {
  const size_t i = (size_t)blockIdx.x * 256 + threadIdx.x;  // 65536 threads
  *(unsigned long long*)(g_hA + i * 4) = 0ULL;              // zero buffer 0
  if (blockIdx.x == 0)
    for (int j = threadIdx.x; j < SYNC_WORDS; j += 256) g_sync[j] = 0;
}

// x[B][S][IN] fp32 -> xA[t][mt][kt][lane][8] fp16 (A-fragment order per step)
__global__ __launch_bounds__(256) void pack_x(const float* __restrict__ x,
                                              half_t* __restrict__ xA) {
  const int t = blockIdx.x, mt = blockIdx.y;
  const int tid = threadIdx.x;
  const int kt = tid >> 7;
  const int lane = (tid >> 1) & 63;
  const int jh = (tid & 1) * 4;
  const int row = mt * 16 + (lane & 15);
  const int k = kt * 32 + (lane >> 4) * 8 + jh;
  const float* s = x + (size_t)row * SS * IND + (size_t)t * IND + k;
  half_t* d = xA + (((size_t)t * 16 + mt) * 2 + kt) * 512 + lane * 8 + jh;
  d[0] = (half_t)s[0]; d[1] = (half_t)s[1];
  d[2] = (half_t)s[2]; d[3] = (half_t)s[3];
}

// row-major fp32 [N][K] -> fp16 B-fragment order [cb][kt][lane][8]
__global__ __launch_bounds__(256) void frag_pack(const float* __restrict__ src,
                                                 half_t* __restrict__ dst, int K) {
  const int cb = blockIdx.x;
  const int tid = threadIdx.x;
  const int lane = tid & 63;
  const int u = tid >> 6;
  const int nkt = K >> 5;
  const int row = cb * 16 + (lane & 15);
  for (int kt = u; kt < nkt; kt += 4) {
    const int k = kt * 32 + (lane >> 4) * 8;
    const float* s = src + (size_t)row * K + k;
    half8 h;
    #pragma unroll
    for (int j = 0; j < 8; ++j) h[j] = (half_t)s[j];
    *(half8*)(dst + ((size_t)cb * nkt + kt) * 512 + lane * 8) = h;
  }
}

// ---------- persistent LSTM kernel (cooperative, 256 WGs = 1/CU) ----------
// 512 threads/WG. Waves 0..3: recurrence (gate g = wave), no barriers in the
// steady state; per-wave u16 release flags. Wave 5 of jtile 63 = aggregator
// (2-hop sync, proven traffic profile). Waves 4..7: dense head paced off an
// LDS step flag -> the head never touches the recurrence critical path.
// XCD clustering: with round-robin bid->XCD (bid&7), each mtile's 64 WGs
// occupy exactly 2 XCDs, so each freshly-written h line is LLC-fetched 2x
// (not 8x) and most consumer h-reads are same-XCD L2 hits.
// B-register cache: kt 0..7 x 4 gates of W fragments (128 VGPR) are loaded
// once before the t-loop; those 32 MFMAs/step never touch LDS, shortening
// the post-go dependent chain and cutting LDS traffic 24%.
__global__ __launch_bounds__(512, 2) void lstm_persistent(
    const float* __restrict__ W_hh, const float* __restrict__ W_ih,
    const float* __restrict__ b_ih, const float* __restrict__ b_hh,
    const half_t* __restrict__ xA, const half_t* __restrict__ Wd_f,
    const float* __restrict__ bd, const half_t* __restrict__ Wd2_f,
    const float* __restrict__ bd2, float* __restrict__ out) {
  extern __shared__ char smem[];
  half_t* Wlds = (half_t*)smem;
  float* pre = (float*)(smem + (size_t)WLDS_HALVES * 2);
  float* dp = (float*)(smem + DP_OFF);          // dense1 partials [3][64][4]
  unsigned* flg = (unsigned*)(smem + FLAG_OFF); // [0..2]=dflag [3]=hstep [4]=ack

  const int bid = blockIdx.x;
  const int xcd = bid & 7;            // round-robin XCD assumption (m09)
  const int mtile = xcd >> 1;         // 0..3  -> XCD pair {2m, 2m+1}
  const int jtile = ((bid >> 3) << 1) | (xcd & 1);  // 0..63, unique per mtile
  const int j0 = jtile * 16;
  const int tid = threadIdx.x;
  const int wave = tid >> 6;
  const int lane = tid & 63;
  const int rn = lane & 15;
  const int kq = lane >> 4;

  // ---- stage W gate-slice into LDS in B-fragment order (8 waves) ----
  {
    const int g = wave & 3;
    const int row = g * HH + j0 + rn;
    for (int kt = (wave >> 2); kt < NKT; kt += 2) {
      const int k = kt * 32 + kq * 8;
      const float* s = (k < HH) ? (W_hh + (size_t)row * HH + k)
                                : (W_ih + (size_t)row * IND + (k - HH));
      half8 hv;
      #pragma unroll
      for (int j = 0; j < 8; ++j) hv[j] = (half_t)s[j];
      *(half8*)(Wlds + ((size_t)g * NKT + kt) * 512 + lane * 8) = hv;
    }
  }
  if (tid < 8) flg[tid] = 0;
  __syncthreads();   // only barrier in the kernel

  unsigned short* slotp =
      (unsigned short*)(g_sync + ((size_t)(mtile * 64 + jtile)) * 32);
  unsigned int* go_base = g_sync + GO_OFF + mtile * 512;
  const unsigned int* gop = go_base + (jtile & 15) * 32;
  unsigned int* dcnt = g_sync + DCNT_OFF + mtile * 32;

  if (wave < 4) {
    // ================= recurrence (gate) waves =================
    const int crow = lane >> 2;         // 0..15 row within wave's block
    const int hl = (lane & 3) * 4;      // col base 0,4,8,12
    float bsum[4][4];
    #pragma unroll
    for (int g = 0; g < 4; ++g) {
      const float4v bi = *(const float4v*)(b_ih + g * HH + j0 + hl);
      const float4v bh = *(const float4v*)(b_hh + g * HH + j0 + hl);
      #pragma unroll
      for (int j = 0; j < 4; ++j) bsum[g][j] = bi[j] + bh[j];
    }
    float4v creg = {0.f, 0.f, 0.f, 0.f};

    const int mtA = mtile * 4 + wave;   // wave's 16-row block (global mt 0..15)
    float* pw = pre + wave * (16 * PRE_STRIDE);

    const int col_s = j0 + hl;
    const int ktw = col_s >> 5;
    const int kqw = (col_s & 31) >> 3;
    const int jw = col_s & 7;
    const size_t hoff =
        (((size_t)(mtA * 32 + ktw)) * 64 + kqw * 16 + crow) * 8 + jw;

    const half_t* habase = g_hA + ((size_t)mtA * 32) * 512 + lane * 8;
    const half_t* bp = Wlds + lane * 8;
    unsigned short* myslot = slotp + wave;

    // ---- persistent B-register cache: kt 0..7, all 4 gates (128 VGPR) ----
    half8 breg0[8], breg1[8], breg2[8], breg3[8];
    #pragma unroll
    for (int kt = 0; kt < 8; ++kt) {
      breg0[kt] = *(const half8*)(bp + (size_t)(0 * NKT + kt) * 512);
      breg1[kt] = *(const half8*)(bp + (size_t)(1 * NKT + kt) * 512);
      breg2[kt] = *(const half8*)(bp + (size_t)(2 * NKT + kt) * 512);
      breg3[kt] = *(const half8*)(bp + (size_t)(3 * NKT + kt) * 512);
    }

    for (int t = 0; t < SS; ++t) {
      float4v a0 = {0.f, 0.f, 0.f, 0.f}, a1 = {0.f, 0.f, 0.f, 0.f};
      float4v a2 = {0.f, 0.f, 0.f, 0.f}, a3 = {0.f, 0.f, 0.f, 0.f};

      // ---- x part first: independent of h_t, hides work under the wait ----
      const half_t* xp = xA + (((size_t)t * 16 + mtA) * 2) * 512 + lane * 8;
      {
        const half8 xv0 = *(const half8*)xp;
        const half8 xv1 = *(const half8*)(xp + 512);
        a0 = MFMA16(xv0, *(const half8*)(bp + (size_t)(0 * NKT + 32) * 512), a0);
        a1 = MFMA16(xv0, *(const half8*)(bp + (size_t)(1 * NKT + 32) * 512), a1);
        a2 = MFMA16(xv0, *(const half8*)(bp + (size_t)(2 * NKT + 32) * 512), a2);
        a3 = MFMA16(xv0, *(const half8*)(bp + (size_t)(3 * NKT + 32) * 512), a3);
        a0 = MFMA16(xv1, *(const half8*)(bp + (size_t)(0 * NKT + 33) * 512), a0);
        a1 = MFMA16(xv1, *(const half8*)(bp + (size_t)(1 * NKT + 33) * 512), a1);
        a2 = MFMA16(xv1, *(const half8*)(bp + (size_t)(2 * NKT + 33) * 512), a2);
        a3 = MFMA16(xv1, *(const half8*)(bp + (size_t)(3 * NKT + 33) * 512), a3);
      }

      // ---- acquire: poll this WG's go line (1 coalesced LLC access/poll) ----
      if (t >= 1) {
        const unsigned tt = (unsigned)t;
        while (__hip_atomic_load(gop, __ATOMIC_RELAXED,
                                 __HIP_MEMORY_SCOPE_AGENT) < tt)
          __builtin_amdgcn_s_sleep(1);
        asm volatile("" ::: "memory");
        if (wave == 0 && lane == 0)   // relay to head waves (LDS, monotonic)
          __hip_atomic_store(&flg[3], tt, __ATOMIC_RELEASE,
                             __HIP_MEMORY_SCOPE_WORKGROUP);
      }

      // ---- h part: kt 0..7 with B from registers (no LDS on the chain) ----
      const half_t* ap = habase + (size_t)t * BUFV;
      #pragma unroll
      for (int kt = 0; kt < 8; ++kt) {
        const half8 av = *(const half8*)(ap + (size_t)kt * 512);
        a0 = MFMA16(av, breg0[kt], a0);
        a1 = MFMA16(av, breg1[kt], a1);
        a2 = MFMA16(av, breg2[kt], a2);
        a3 = MFMA16(av, breg3[kt], a3);
      }
      // ---- kt 8..31 with B from LDS ----
      #pragma unroll 8
      for (int kt = 8; kt < 32; ++kt) {
        const half8 av = *(const half8*)(ap + (size_t)kt * 512);
        a0 = MFMA16(av, *(const half8*)(bp + (size_t)(0 * NKT + kt) * 512), a0);
        a1 = MFMA16(av, *(const half8*)(bp + (size_t)(1 * NKT + kt) * 512), a1);
        a2 = MFMA16(av, *(const half8*)(bp + (size_t)(2 * NKT + kt) * 512), a2);
        a3 = MFMA16(av, *(const half8*)(bp + (size_t)(3 * NKT + kt) * 512), a3);
      }

      // ---- intra-wave pre-activation exchange (no barrier) ----
      #pragma unroll
      for (int r = 0; r < 4; ++r) {
        const int rl = (kq * 4 + r) * PRE_STRIDE;
        pw[rl + rn] = a0[r];
        pw[rl + 16 + rn] = a1[r];
        pw[rl + 32 + rn] = a2[r];
        pw[rl + 48 + rn] = a3[r];
      }

      // ---- cell update (c in registers) ----
      const float4v pg0 = *(const float4v*)(pw + crow * PRE_STRIDE + hl);
      const float4v pg1 = *(const float4v*)(pw + crow * PRE_STRIDE + 16 + hl);
      const float4v pg2 = *(const float4v*)(pw + crow * PRE_STRIDE + 32 + hl);
      const float4v pg3 = *(const float4v*)(pw + crow * PRE_STRIDE + 48 + hl);
      half4 hnew;
      #pragma unroll
      for (int jj = 0; jj < 4; ++jj) {
        const float ig = pg0[jj] + bsum[0][jj];
        const float fg = pg1[jj] + bsum[1][jj];
        const float gg = pg2[jj] + bsum[2][jj];
        const float og = pg3[jj] + bsum[3][jj];
        const float is = 1.f / (1.f + __expf(-ig));
        const float fs = 1.f / (1.f + __expf(-fg));
        const float os = 1.f / (1.f + __expf(-og));
        const float gt = tanhf(gg);
        const float cn = fs * creg[jj] + is * gt;
        creg[jj] = cn;
        hnew[jj] = (half_t)(os * tanhf(cn));
      }
      astore8(g_hA + (size_t)(t + 1) * BUFV + hoff, hnew);

      // ---- release: own rows at LLC, publish own per-wave u16 slot ----
      __builtin_amdgcn_s_waitcnt(0);
      if (lane == 0)
        __hip_atomic_store(myslot, (unsigned short)(t + 1), __ATOMIC_RELAXED,
                           __HIP_MEMORY_SCOPE_AGENT);
    }

    // final relay so head waves can process h_SS
    if (wave == 0) {
      while (__hip_atomic_load(gop, __ATOMIC_RELAXED,
                               __HIP_MEMORY_SCOPE_AGENT) < (unsigned)SS)
        __builtin_amdgcn_s_sleep(1);
      asm volatile("" ::: "memory");
      if (lane == 0)
        __hip_atomic_store(&flg[3], (unsigned)SS, __ATOMIC_RELEASE,
                           __HIP_MEMORY_SCOPE_WORKGROUP);
    }

  } else if (jtile < 32) {
    // ================= dense1 head waves (4-way K split) =================
    const int u = wave - 4;             // 0..3: ktiles u*8 .. u*8+7
    const int rb = jtile >> 3, cb = jtile & 7;
    const int mt = mtile * 4 + rb;
    const half_t* hb = g_hA + ((size_t)mt * 32 + u * 8) * 512 + lane * 8;
    const half_t* bb = Wd_f + ((size_t)cb * 32 + u * 8) * 512 + lane * 8;

    for (int s = 1; s <= SS; ++s) {
      while (__hip_atomic_load(&flg[3], __ATOMIC_ACQUIRE,
                               __HIP_MEMORY_SCOPE_WORKGROUP) < (unsigned)s)
        __builtin_amdgcn_s_sleep(2);
      asm volatile("" ::: "memory");

      const half_t* ap = hb + (size_t)s * BUFV;
      float4v acc = {0.f, 0.f, 0.f, 0.f};
      #pragma unroll
      for (int kt = 0; kt < 8; ++kt)
        acc = MFMA16(*(const half8*)(ap + (size_t)kt * 512),
                     *(const half8*)(bb + (size_t)kt * 512), acc);

      if (u) {
        // back-pressure: wave 4 must have consumed step s-1 partials
        if (s > 1)
          while (__hip_atomic_load(&flg[4], __ATOMIC_ACQUIRE,
                                   __HIP_MEMORY_SCOPE_WORKGROUP) <
                 (unsigned)(s - 1))
            __builtin_amdgcn_s_sleep(1);
        *(float4v*)(dp + ((size_t)(u - 1) * 64 + lane) * 4) = acc;
        __hip_atomic_store(&flg[u - 1], (unsigned)s, __ATOMIC_RELEASE,
                           __HIP_MEMORY_SCOPE_WORKGROUP);
      } else {
        for (;;) {
          const unsigned f0 = __hip_atomic_load(&flg[0], __ATOMIC_ACQUIRE,
                                                __HIP_MEMORY_SCOPE_WORKGROUP);
          const unsigned f1 = __hip_atomic_load(&flg[1], __ATOMIC_ACQUIRE,
                                                __HIP_MEMORY_SCOPE_WORKGROUP);
          const unsigned f2 = __hip_atomic_load(&flg[2], __ATOMIC_ACQUIRE,
                                                __HIP_MEMORY_SCOPE_WORKGROUP);
          if (f0 >= (unsigned)s && f1 >= (unsigned)s && f2 >= (unsigned)s) break;
          __builtin_amdgcn_s_sleep(1);
        }
        asm volatile("" ::: "memory");
        #pragma unroll
        for (int i = 0; i < 3; ++i) {
          const float4v p = *(const float4v*)(dp + ((size_t)i * 64 + lane) * 4);
          #pragma unroll
          for (int r = 0; r < 4; ++r) acc[r] += p[r];
        }
        __hip_atomic_store(&flg[4], (unsigned)s, __ATOMIC_RELEASE,
                           __HIP_MEMORY_SCOPE_WORKGROUP);  // ack producers
        const int dcol = cb * 16 + rn;
        const float bv = bd[dcol];
        half_t* db = g_dbuf + (((size_t)(s - 1) * 16 + mt) * 16) * HEADD + dcol;
        #pragma unroll
        for (int r = 0; r < 4; ++r)
          astore2(db + (size_t)(kq * 4 + r) * HEADD,
                  (half_t)fmaxf(acc[r] + bv, 0.f));
        __builtin_amdgcn_s_waitcnt(0);
        if (lane == 0)
          __hip_atomic_fetch_add(dcnt, 1u, __ATOMIC_RELAXED,
                                 __HIP_MEMORY_SCOPE_AGENT);
      }
    }

  } else if (jtile < 48 && wave == 4) {
    // ================= dense2 head wave =================
    const int task = jtile - 32;
    const int rb = task >> 2, cb2 = task & 3;
    const int mt = mtile * 4 + rb;
    const int m0 = mtile * 64;
    const half_t* bp2 = Wd2_f + (size_t)cb2 * 4 * 512 + lane * 8;
    for (int d = 0; d < SS; ++d) {
      if (lane == 0) {
        const unsigned tgt = 32u * (unsigned)(d + 1);
        while (__hip_atomic_load(dcnt, __ATOMIC_RELAXED,
                                 __HIP_MEMORY_SCOPE_AGENT) < tgt)
          __builtin_amdgcn_s_sleep(16);
      }
      asm volatile("" ::: "memory");
      const half_t* ap = g_dbuf + (((size_t)d * 16 + mt) * 16) * HEADD;
      float4v acc = {0.f, 0.f, 0.f, 0.f};
      #pragma unroll
      for (int kt = 0; kt < 4; ++kt) {
        const half8 af =
            *(const half8*)(ap + (size_t)rn * HEADD + kt * 32 + kq * 8);
        acc = MFMA16(af, *(const half8*)(bp2 + (size_t)kt * 512), acc);
      }
      const int ocol = cb2 * 16 + rn;
      const float bv = bd2[ocol];
      #pragma unroll
      for (int r = 0; r < 4; ++r) {
        const int row = m0 + rb * 16 + kq * 4 + r;
        out[(size_t)row * (SS * OUTD) + (size_t)d * OUTD + ocol] = acc[r] + bv;
      }
    }

  } else if (jtile == 63 && wave == 5) {
    // ================= aggregator wave (one per mtile) =================
    const unsigned long long* pollp =
        (const unsigned long long*)(g_sync + ((size_t)(mtile * 64 + lane)) * 32);
    for (int t = 1; t <= SS; ++t) {
      const unsigned tt = (unsigned)t;
      for (;;) {
        const unsigned long long v = __hip_atomic_load(
            pollp, __ATOMIC_RELAXED, __HIP_MEMORY_SCOPE_AGENT);
        const unsigned f0 = (unsigned)(v & 0xffffu);
        const unsigned f1 = (unsigned)((v >> 16) & 0xffffu);
        const unsigned f2 = (unsigned)((v >> 32) & 0xffffu);
        const unsigned f3 = (unsigned)(v >> 48);
        if (__all((int)(f0 >= tt && f1 >= tt && f2 >= tt && f3 >= tt))) break;
        __builtin_amdgcn_s_sleep(1);
      }
      asm volatile("" ::: "memory");
      if (lane < 16)
        __hip_atomic_store(go_base + lane * 32, tt, __ATOMIC_RELAXED,
                           __HIP_MEMORY_SCOPE_AGENT);
    }
  }
}

extern "C" void kernel_launch(void* const* d_in, const int* in_sizes, int n_in,
                              void* d_out, int out_size, void* d_ws, size_t ws_size,
                              hipStream_t stream) {
  const float* x        = (const float*)d_in[0];
  const float* W_ih     = (const float*)d_in[1];
  const float* b_ih     = (const float*)d_in[2];
  const float* W_hh     = (const float*)d_in[3];
  const float* b_hh     = (const float*)d_in[4];
  const float* W_dense  = (const float*)d_in[5];
  const float* b_dense  = (const float*)d_in[6];
  const float* W_dense2 = (const float*)d_in[7];
  const float* b_dense2 = (const float*)d_in[8];
  float* out = (float*)d_out;

  char* p = (char*)d_ws;
  half_t* xA    = (half_t*)p; p += (size_t)SS * 16 * 1024 * 2;  // 16.8 MB
  half_t* Wd_f  = (half_t*)p; p += (size_t)8 * 32 * 512 * 2;    // 256 KB
  half_t* Wd2_f = (half_t*)p; p += (size_t)4 * 4 * 512 * 2;     // 16 KB

  init_state<<<256, 256, 0, stream>>>();
  pack_x<<<dim3(SS, 16), 256, 0, stream>>>(x, xA);
  frag_pack<<<HEADD / 16, 256, 0, stream>>>(W_dense, Wd_f, HH);
  frag_pack<<<OUTD / 16, 256, 0, stream>>>(W_dense2, Wd2_f, HEADD);

  hipFuncSetAttribute((const void*)lstm_persistent,
                      hipFuncAttributeMaxDynamicSharedMemorySize, SMEM_BYTES);
  void* args[] = {(void*)&W_hh, (void*)&W_ih, (void*)&b_ih, (void*)&b_hh,
                  (void*)&xA, (void*)&Wd_f, (void*)&b_dense,
                  (void*)&Wd2_f, (void*)&b_dense2, (void*)&out};
  hipLaunchCooperativeKernel((void*)lstm_persistent, dim3(256), dim3(512),
                             args, SMEM_BYTES, stream);
}